// Round 2
// baseline (174.306 us; speedup 1.0000x reference)
//
#include <hip/hip_runtime.h>
#include <hip/hip_bf16.h>

typedef __attribute__((ext_vector_type(4))) float f32x4;
typedef __attribute__((ext_vector_type(8))) short bf16x8;
typedef __attribute__((ext_vector_type(4))) short bf16x4;

#define QS_STRIDE 68   // 64 + 4 pad floats, 272B rows
#define BT_STRIDE 72   // 64 + 8 pad shorts, 144B rows (16B-aligned for b128 reads)

__device__ __forceinline__ short f2bf(float x) {
    __hip_bfloat16 h = __float2bfloat16(x);   // RNE; compiler pairs into v_cvt_pk_bf16_f32
    return __builtin_bit_cast(short, h);
}

// barrier WITHOUT vmcnt drain: LDS-ordering only; global prefetch stays in flight
#define FENCE() do {                                         \
    asm volatile("s_waitcnt lgkmcnt(0)" ::: "memory");       \
    __builtin_amdgcn_s_barrier();                            \
    asm volatile("" ::: "memory");                           \
} while (0)

__global__ __launch_bounds__(256) void quad_form_kernel(
    const float* __restrict__ q, const float* __restrict__ kv, float* __restrict__ out)
{
    __shared__ float qs[128 * QS_STRIDE];                          // 34816 B
    __shared__ __align__(16) unsigned short Bt[2][64 * BT_STRIDE]; // 18432 B

    const int tid = threadIdx.x;

    // XCD-aware swizzle: both c-halves of a chunk on the same XCD
    const int wg = blockIdx.x;            // 0..255
    const int x = wg & 7, p = wg >> 3;    // p: 0..31
    const int chunk = x * 16 + (p >> 1);  // 0..127
    const int half = p & 1;

    const float* qch = q   + (size_t)chunk * (256 * 64) + half * (128 * 64);
    const float* Sch = kv  + (size_t)chunk * 262144;
    float*       och = out + (size_t)chunk * (256 * 64) + half * (128 * 64);

    // ---- stage q half-chunk (128x64) into LDS as fp32, scaled by 1/8 ----
#pragma unroll
    for (int i = 0; i < 8; ++i) {
        int idx4 = i * 256 + tid;
        int row = idx4 >> 4;
        int col = (idx4 & 15) << 2;
        f32x4 v = *(const f32x4*)(qch + idx4 * 4);
        v *= 0.125f;
        *(f32x4*)&qs[row * QS_STRIDE + col] = v;
    }

    // ---- staging mapping: thread -> (f = tid&63, k-quarter = tid>>6) ----
    const int fS = tid & 63;
    const int kq = tid >> 6;
    const int rot = (fS >> 3) & 3;        // bank-spread rotation for ds_writes
    const float* Sptr = Sch + fS + kq * 16 * 64;

    float r0[16], r1[16], r2[16], r3[16];

    auto issue = [&](float* r, int d0) {
        const float* p0 = Sptr + d0 * 4096;
#pragma unroll
        for (int i = 0; i < 16; ++i)
            r[i] = p0[i * 64];            // coalesced dwords, imm offsets
    };
    auto stage = [&](const float* r, int buf) {
        unsigned short* base = &Bt[buf][fS * BT_STRIDE + kq * 16];
#pragma unroll
        for (int i4 = 0; i4 < 4; ++i4) {
            int w = (i4 + rot) & 3;       // per-lane rotated issue order, same final layout
            bf16x4 wv;
#pragma unroll
            for (int j = 0; j < 4; ++j) wv[j] = f2bf(r[w * 4 + j]);
            *(bf16x4*)(base + w * 4) = wv;
        }
    };

    // ---- MFMA geometry: 4 waves, each 32 c-rows (2 M-tiles) x 64 f (4 N-tiles) ----
    const int lane = tid & 63;
    const int w = tid >> 6;
    const int lr0 = w * 32;
    const int ra = lane & 15;
    const int kg = lane >> 4;

    f32x4 acc[2][4] = {};

    const float* qrow0 = qs + (lr0 + ra) * QS_STRIDE;
    const float* qrow1 = qs + (lr0 + 16 + ra) * QS_STRIDE;

    auto mfma_phase = [&](int buf, int d0) {
        float s0 = qrow0[d0];
        float s1 = qrow1[d0];
#pragma unroll
        for (int Ks = 0; Ks < 2; ++Ks) {
            int e0 = Ks * 32 + kg * 8;
            f32x4 u00 = *(const f32x4*)(qrow0 + e0);
            f32x4 u01 = *(const f32x4*)(qrow0 + e0 + 4);
            f32x4 u10 = *(const f32x4*)(qrow1 + e0);
            f32x4 u11 = *(const f32x4*)(qrow1 + e0 + 4);
            bf16x8 a0, a1;
#pragma unroll
            for (int j = 0; j < 4; ++j) {
                a0[j]     = f2bf(s0 * u00[j]);
                a0[j + 4] = f2bf(s0 * u01[j]);
                a1[j]     = f2bf(s1 * u10[j]);
                a1[j + 4] = f2bf(s1 * u11[j]);
            }
#pragma unroll
            for (int Nt = 0; Nt < 4; ++Nt) {
                bf16x8 b = *(const bf16x8*)&Bt[buf][(Nt * 16 + ra) * BT_STRIDE + e0];
                acc[0][Nt] = __builtin_amdgcn_mfma_f32_16x16x32_bf16(a0, b, acc[0][Nt], 0, 0, 0);
                acc[1][Nt] = __builtin_amdgcn_mfma_f32_16x16x32_bf16(a1, b, acc[1][Nt], 0, 0, 0);
            }
        }
    };

    // ---- K-loop: 4-deep register prefetch, 1 LDS-only barrier per slice ----
    issue(r0, 0); issue(r1, 1); issue(r2, 2); issue(r3, 3);
    stage(r0, 0);
    issue(r0, 4);
    FENCE();

#pragma unroll 1
    for (int d0 = 0; d0 < 64; d0 += 4) {
        stage(r1, 1); if (d0 + 5 < 64) issue(r1, d0 + 5);
        mfma_phase(0, d0);
        FENCE();

        stage(r2, 0); if (d0 + 6 < 64) issue(r2, d0 + 6);
        mfma_phase(1, d0 + 1);
        FENCE();

        stage(r3, 1); if (d0 + 7 < 64) issue(r3, d0 + 7);
        mfma_phase(0, d0 + 2);
        FENCE();

        if (d0 + 4 < 64) stage(r0, 0);
        if (d0 + 8 < 64) issue(r0, d0 + 8);
        mfma_phase(1, d0 + 3);
        FENCE();
    }

    // ---- epilogue: out = 0.5 * acc ----
#pragma unroll
    for (int Mt = 0; Mt < 2; ++Mt)
#pragma unroll
        for (int Nt = 0; Nt < 4; ++Nt)
#pragma unroll
            for (int j = 0; j < 4; ++j) {
                int r = lr0 + Mt * 16 + kg * 4 + j;
                och[r * 64 + Nt * 16 + ra] = 0.5f * acc[Mt][Nt][j];
            }
}

extern "C" void kernel_launch(void* const* d_in, const int* in_sizes, int n_in,
                              void* d_out, int out_size, void* d_ws, size_t ws_size,
                              hipStream_t stream) {
    const float* q  = (const float*)d_in[0];
    const float* kv = (const float*)d_in[1];
    float* out = (float*)d_out;
    hipLaunchKernelGGL(quad_form_kernel, dim3(256), dim3(256), 0, stream, q, kv, out);
}

// Round 3
// 47.880 us; speedup vs baseline: 3.6405x; 3.6405x over previous
//
#include <hip/hip_runtime.h>
#include <hip/hip_bf16.h>

typedef __attribute__((ext_vector_type(4))) float f32x4;
typedef __attribute__((ext_vector_type(8))) short bf16x8;
typedef __attribute__((ext_vector_type(4))) short bf16x4;

#define QS_STRIDE 68   // 64 + 4 pad floats, 272B rows (16B-aligned, 2-way = free)
#define BT_STRIDE 72   // 64 + 8 pad shorts, 144B rows (16B-aligned)

__device__ __forceinline__ short f2bf(float x) {
    __hip_bfloat16 h = __float2bfloat16(x);   // RNE; pairs into v_cvt_pk_bf16_f32
    return __builtin_bit_cast(short, h);
}

// LDS-ordering barrier WITHOUT vmcnt drain: global prefetch stays in flight
#define FENCE() do {                                         \
    asm volatile("s_waitcnt lgkmcnt(0)" ::: "memory");       \
    __builtin_amdgcn_s_barrier();                            \
    asm volatile("" ::: "memory");                           \
} while (0)

__global__ __launch_bounds__(256, 2) void quad_form_kernel(
    const float* __restrict__ q, const float* __restrict__ kv, float* __restrict__ out)
{
    __shared__ float qs[64 * QS_STRIDE];                           // 17408 B
    __shared__ __align__(16) unsigned short Bt[2][64 * BT_STRIDE]; // 18432 B

    const int tid = threadIdx.x;

    // XCD swizzle: all 4 quarter-WGs of a chunk land on the same XCD (wg%8 round-robin)
    const int wg = blockIdx.x;            // 0..511
    const int xcd = wg & 7, p = wg >> 3;  // p: 0..63
    const int chunk = xcd * 16 + (p >> 2);// 0..127
    const int quarter = p & 3;

    const float* qch = q   + (size_t)chunk * (256 * 64) + quarter * (64 * 64);
    const float* Sch = kv  + (size_t)chunk * 262144;
    float*       och = out + (size_t)chunk * (256 * 64) + quarter * (64 * 64);

    // ---- stage q quarter-chunk (64x64) into LDS fp32, scaled by 1/8 (exact) ----
#pragma unroll
    for (int i = 0; i < 4; ++i) {
        int idx4 = i * 256 + tid;          // 0..1023
        int row = idx4 >> 4;
        int col = (idx4 & 15) << 2;
        f32x4 v = *(const f32x4*)(qch + idx4 * 4);
        v *= 0.125f;
        *(f32x4*)&qs[row * QS_STRIDE + col] = v;
    }

    // ---- S staging map: wave = k-quarter, lane = f column ----
    const int fS = tid & 63;
    const int kq = tid >> 6;
    const float* Sptr = Sch + fS + kq * (16 * 64);

    float r0[16], r1[16];

    auto issue = [&](float* r, int d0) {
        const float* p0 = Sptr + d0 * 4096;
#pragma unroll
        for (int i = 0; i < 16; ++i)
            r[i] = p0[i * 64];             // coalesced dwords, imm offsets (<=3840B)
    };
    auto stage = [&](const float* r, int buf) {
        unsigned short* base = &Bt[buf][fS * BT_STRIDE + kq * 16];
#pragma unroll
        for (int i4 = 0; i4 < 4; ++i4) {
            bf16x4 wv;
#pragma unroll
            for (int j = 0; j < 4; ++j) wv[j] = f2bf(r[i4 * 4 + j]);
            *(bf16x4*)(base + i4 * 4) = wv;  // [f][k] transposed layout
        }
    };

    // ---- MFMA geometry: 4 waves, each ONE 16-row M-tile x 64 f (4 N-tiles) ----
    const int lane = tid & 63;
    const int w = tid >> 6;
    const int ra = lane & 15;
    const int kg = lane >> 4;

    f32x4 acc[4] = {};
    const float* qrow = qs + (w * 16 + ra) * QS_STRIDE;

    auto mfma_phase = [&](int buf, int d0) {
        float s0 = qrow[d0];
#pragma unroll
        for (int Ks = 0; Ks < 2; ++Ks) {
            int e0 = Ks * 32 + kg * 8;
            f32x4 u0 = *(const f32x4*)(qrow + e0);
            f32x4 u1 = *(const f32x4*)(qrow + e0 + 4);
            bf16x8 a;
#pragma unroll
            for (int j = 0; j < 4; ++j) {
                a[j]     = f2bf(s0 * u0[j]);
                a[j + 4] = f2bf(s0 * u1[j]);
            }
#pragma unroll
            for (int Nt = 0; Nt < 4; ++Nt) {
                bf16x8 b = *(const bf16x8*)&Bt[buf][(Nt * 16 + ra) * BT_STRIDE + e0];
                acc[Nt] = __builtin_amdgcn_mfma_f32_16x16x32_bf16(a, b, acc[Nt], 0, 0, 0);
            }
        }
    };

    // ---- K-loop: slice i staged at phase i-1, its loads issued at phase i-3 ----
    issue(r0, 0); issue(r1, 1);
    stage(r0, 0);
    issue(r0, 2);
    FENCE();

    for (int i = 0; i < 64; i += 2) {
        stage(r1, 1);                       // slice i+1 -> buf1
        if (i + 3 < 64) issue(r1, i + 3);
        mfma_phase(0, i);
        FENCE();

        if (i + 2 < 64) {
            stage(r0, 0);                   // slice i+2 -> buf0
            if (i + 4 < 64) issue(r0, i + 4);
        }
        mfma_phase(1, i + 1);
        FENCE();
    }

    // ---- epilogue: out = 0.5 * acc ----
#pragma unroll
    for (int Nt = 0; Nt < 4; ++Nt)
#pragma unroll
        for (int j = 0; j < 4; ++j) {
            int r = w * 16 + kg * 4 + j;
            och[r * 64 + Nt * 16 + ra] = 0.5f * acc[Nt][j];
        }
}

extern "C" void kernel_launch(void* const* d_in, const int* in_sizes, int n_in,
                              void* d_out, int out_size, void* d_ws, size_t ws_size,
                              hipStream_t stream) {
    const float* q  = (const float*)d_in[0];
    const float* kv = (const float*)d_in[1];
    float* out = (float*)d_out;
    hipLaunchKernelGGL(quad_form_kernel, dim3(512), dim3(256), 0, stream, q, kv, out);
}

// Round 4
// 47.524 us; speedup vs baseline: 3.6677x; 1.0075x over previous
//
#include <hip/hip_runtime.h>
#include <hip/hip_bf16.h>

typedef __attribute__((ext_vector_type(4))) float f32x4;
typedef __attribute__((ext_vector_type(8))) short bf16x8;
typedef __attribute__((ext_vector_type(4))) short bf16x4;

#define QS_STRIDE 68   // 64 + 4 pad floats (272B rows; b32 reads 2-way = free)
#define BT_STRIDE 72   // 64 + 8 pad shorts (144B rows, 16B-aligned for b128)

static __device__ __forceinline__ short f2bf(float x) {
    __hip_bfloat16 h = __float2bfloat16(x);   // RNE; pairs into v_cvt_pk_bf16_f32
    return __builtin_bit_cast(short, h);
}

// LDS-ordering barrier WITHOUT vmcnt drain: global prefetch stays in flight
#define FENCE() do {                                         \
    asm volatile("s_waitcnt lgkmcnt(0)" ::: "memory");       \
    __builtin_amdgcn_s_barrier();                            \
    asm volatile("" ::: "memory");                           \
} while (0)

__global__ __launch_bounds__(256, 2) void quad_form_kernel(
    const float* __restrict__ q, const float* __restrict__ kv, float* __restrict__ out)
{
    __shared__ float qs[64 * QS_STRIDE];                           // 17408 B
    __shared__ __align__(16) unsigned short Bt[2][64 * BT_STRIDE]; // 18432 B

    const int tid = threadIdx.x;

    // XCD swizzle: all 4 quarter-WGs of a chunk on one XCD (wg%8 round-robin)
    const int wg = blockIdx.x;            // 0..511
    const int xcd = wg & 7, p = wg >> 3;  // p: 0..63
    const int chunk = xcd * 16 + (p >> 2);
    const int quarter = p & 3;

    const float* qch = q   + (size_t)chunk * 16384 + quarter * 4096;
    const float* Sch = kv  + (size_t)chunk * 262144;
    float*       och = out + (size_t)chunk * 16384 + quarter * 4096;

    // ---- stage q quarter (64x64) into LDS fp32, scaled by 1/8 (exact) ----
#pragma unroll
    for (int i = 0; i < 4; ++i) {
        int idx4 = i * 256 + tid;
        int row = idx4 >> 4, col = (idx4 & 15) << 2;
        f32x4 v = *(const f32x4*)(qch + idx4 * 4);
        v *= 0.125f;
        *(f32x4*)&qs[row * QS_STRIDE + col] = v;
    }

    // ---- S staging map: wave = k-quarter, lane = f column (coalesced dwords) ----
    const int fS = tid & 63;
    const int kq = tid >> 6;
    const float* Sptr = Sch + fS + kq * 1024;   // kq*16 rows of 64

    float r0[16], r1[16], r2[16];

    auto issue = [&](float* r, int d0) {
        const float* p0 = Sptr + d0 * 4096;
#pragma unroll
        for (int i = 0; i < 16; ++i)
            r[i] = p0[i * 64];                  // imm offsets <= 3840B
    };
    auto stage = [&](const float* r, int buf) {
        unsigned short* base = &Bt[buf][fS * BT_STRIDE + kq * 16];
#pragma unroll
        for (int i4 = 0; i4 < 4; ++i4) {
            bf16x4 wv;
#pragma unroll
            for (int j = 0; j < 4; ++j) wv[j] = f2bf(r[i4 * 4 + j]);
            *(bf16x4*)(base + i4 * 4) = wv;     // [f][k] transposed layout
        }
    };

    // ---- MFMA geometry: 4 waves in 2x2; wave = 32 rows x 32 cols (2Mt x 2Nt) ----
    const int lane = tid & 63;
    const int w = tid >> 6;
    const int wm = w & 1, wn = w >> 1;
    const int ra = lane & 15, kg = lane >> 4;

    f32x4 acc[2][2] = {};
    const float* qrow0 = qs + (wm * 32 + ra) * QS_STRIDE;
    const float* qrow1 = qrow0 + 16 * QS_STRIDE;

    // ---- prologue: fill pipeline ----
    issue(r0, 0); issue(r1, 1); issue(r2, 2);
    stage(r0, 0);
    issue(r0, 3);
    FENCE();

    // ---- hoist loop-invariant e-segments into registers (fence-clobber-proof) ----
    f32x4 u[2][2][2];
#pragma unroll
    for (int Mt = 0; Mt < 2; ++Mt) {
        const float* qr = Mt ? qrow1 : qrow0;
#pragma unroll
        for (int Ks = 0; Ks < 2; ++Ks) {
            u[Mt][Ks][0] = *(const f32x4*)(qr + Ks * 32 + kg * 8);
            u[Mt][Ks][1] = *(const f32x4*)(qr + Ks * 32 + kg * 8 + 4);
        }
    }
    float s0c = qrow0[0], s1c = qrow1[0];

    auto mfma_phase = [&](int buf, float s0, float s1) {
#pragma unroll
        for (int Ks = 0; Ks < 2; ++Ks) {
            const int e0 = Ks * 32 + kg * 8;
            bf16x8 a0, a1;
#pragma unroll
            for (int j = 0; j < 4; ++j) {
                a0[j]     = f2bf(s0 * u[0][Ks][0][j]);
                a0[j + 4] = f2bf(s0 * u[0][Ks][1][j]);
                a1[j]     = f2bf(s1 * u[1][Ks][0][j]);
                a1[j + 4] = f2bf(s1 * u[1][Ks][1][j]);
            }
#pragma unroll
            for (int Nt = 0; Nt < 2; ++Nt) {
                bf16x8 b = *(const bf16x8*)&Bt[buf][(wn * 32 + Nt * 16 + ra) * BT_STRIDE + e0];
                acc[0][Nt] = __builtin_amdgcn_mfma_f32_16x16x32_bf16(a0, b, acc[0][Nt], 0, 0, 0);
                acc[1][Nt] = __builtin_amdgcn_mfma_f32_16x16x32_bf16(a1, b, acc[1][Nt], 0, 0, 0);
            }
        }
    };

    // ---- K-loop: 3-phase rotation, slice i+1 staged at phase i (loads 3 phases old) ----
    int i = 0;
    auto phase = [&](float* rb) {
        stage(rb, (i + 1) & 1);                 // slice i+1 -> Bt[(i+1)&1]
        if (i + 4 < 64) issue(rb, i + 4);       // refill, consumed at phase i+3
        mfma_phase(i & 1, s0c, s1c);            // slice i from Bt[i&1]
        float ns0 = qrow0[i + 1], ns1 = qrow1[i + 1];  // next diag scale (reg-carried)
        FENCE();
        s0c = ns0; s1c = ns1;
        ++i;
    };

#pragma unroll 1
    for (int it = 0; it < 21; ++it) {           // phases 0..62
        phase(r1); phase(r2); phase(r0);
    }
    mfma_phase(1, s0c, s1c);                    // tail: slice 63 from Bt[1]

    // ---- epilogue: out = 0.5 * acc ----
#pragma unroll
    for (int Mt = 0; Mt < 2; ++Mt)
#pragma unroll
        for (int Nt = 0; Nt < 2; ++Nt)
#pragma unroll
            for (int j = 0; j < 4; ++j) {
                int r = wm * 32 + Mt * 16 + kg * 4 + j;
                int c = wn * 32 + Nt * 16 + ra;
                och[r * 64 + c] = 0.5f * acc[Mt][Nt][j];
            }
}

extern "C" void kernel_launch(void* const* d_in, const int* in_sizes, int n_in,
                              void* d_out, int out_size, void* d_ws, size_t ws_size,
                              hipStream_t stream) {
    const float* q  = (const float*)d_in[0];
    const float* kv = (const float*)d_in[1];
    float* out = (float*)d_out;
    hipLaunchKernelGGL(quad_form_kernel, dim3(512), dim3(256), 0, stream, q, kv, out);
}